// Round 1
// baseline (90.891 us; speedup 1.0000x reference)
//
#include <hip/hip_runtime.h>

// score[e] = dot(h_src[src_idx[e]], h_dst[dst_idx[e]]), D = 128.
// One 32-lane group per edge: lane l loads float4 #l of each row (32*16B = 512B = full row),
// per-lane partial dot, then 5-step shfl_xor butterfly reduce, lane 0 stores.

#define FEAT_D 128

__global__ __launch_bounds__(256) void edge_dot_kernel(
    const float* __restrict__ h_src,
    const float* __restrict__ h_dst,
    const int*   __restrict__ src_idx,
    const int*   __restrict__ dst_idx,
    float*       __restrict__ out,
    int E)
{
    long gtid = (long)blockIdx.x * blockDim.x + threadIdx.x;
    int edge = (int)(gtid >> 5);
    if (edge >= E) return;
    int lane = (int)(threadIdx.x & 31);

    long s = src_idx[edge];
    long t = dst_idx[edge];

    float4 a = reinterpret_cast<const float4*>(h_src + s * FEAT_D)[lane];
    float4 b = reinterpret_cast<const float4*>(h_dst + t * FEAT_D)[lane];

    float sum = a.x * b.x + a.y * b.y + a.z * b.z + a.w * b.w;

    #pragma unroll
    for (int off = 16; off >= 1; off >>= 1)
        sum += __shfl_xor(sum, off);

    if (lane == 0) out[edge] = sum;
}

extern "C" void kernel_launch(void* const* d_in, const int* in_sizes, int n_in,
                              void* d_out, int out_size, void* d_ws, size_t ws_size,
                              hipStream_t stream) {
    const float* h_src  = (const float*)d_in[0];
    const float* h_dst  = (const float*)d_in[1];
    const int*   src_idx = (const int*)d_in[2];
    const int*   dst_idx = (const int*)d_in[3];
    float* out = (float*)d_out;

    int E = in_sizes[2];  // number of edges

    long total_threads = (long)E * 32;
    int block = 256;
    long grid = (total_threads + block - 1) / block;

    edge_dot_kernel<<<(unsigned)grid, block, 0, stream>>>(h_src, h_dst, src_idx, dst_idx, out, E);
}

// Round 2
// 89.475 us; speedup vs baseline: 1.0158x; 1.0158x over previous
//
#include <hip/hip_runtime.h>

// score[e] = dot(h_src[src_idx[e]], h_dst[dst_idx[e]]), D = 128.
// One 32-lane group per EPG=4 consecutive edges: lane l loads float4 #l of each
// row. All 8 row loads issued before any reduction -> 4x memory-level
// parallelism per wave vs the 1-edge-per-group version. 5-step shfl_xor
// butterfly per edge, lane 0 stores a float4 of 4 scores.

#define FEAT_D 128
#define EPG 4  // edges per 32-lane group

__global__ __launch_bounds__(256) void edge_dot_kernel(
    const float* __restrict__ h_src,
    const float* __restrict__ h_dst,
    const int*   __restrict__ src_idx,
    const int*   __restrict__ dst_idx,
    float*       __restrict__ out,
    int E)
{
    long gtid = (long)blockIdx.x * blockDim.x + threadIdx.x;
    int group = (int)(gtid >> 5);
    int lane  = (int)(threadIdx.x & 31);
    int e0 = group * EPG;
    if (e0 >= E) return;

    // Load all indices first (broadcast within the group, L1-served).
    int sidx[EPG], tidx[EPG];
    #pragma unroll
    for (int i = 0; i < EPG; ++i) {
        int e = e0 + i;
        int ec = (e < E) ? e : (E - 1);
        sidx[i] = src_idx[ec];
        tidx[i] = dst_idx[ec];
    }

    // Issue all row loads back-to-back (8 independent global_load_dwordx4).
    float4 a[EPG], b[EPG];
    #pragma unroll
    for (int i = 0; i < EPG; ++i)
        a[i] = reinterpret_cast<const float4*>(h_src + (long)sidx[i] * FEAT_D)[lane];
    #pragma unroll
    for (int i = 0; i < EPG; ++i)
        b[i] = reinterpret_cast<const float4*>(h_dst + (long)tidx[i] * FEAT_D)[lane];

    // Per-edge partial dot + butterfly reduce across the 32-lane group.
    float sum[EPG];
    #pragma unroll
    for (int i = 0; i < EPG; ++i) {
        float s = a[i].x * b[i].x + a[i].y * b[i].y + a[i].z * b[i].z + a[i].w * b[i].w;
        #pragma unroll
        for (int off = 16; off >= 1; off >>= 1)
            s += __shfl_xor(s, off);
        sum[i] = s;
    }

    if (lane == 0) {
        if (e0 + EPG <= E) {
            *reinterpret_cast<float4*>(out + e0) = make_float4(sum[0], sum[1], sum[2], sum[3]);
        } else {
            for (int i = 0; i < EPG && e0 + i < E; ++i) out[e0 + i] = sum[i];
        }
    }
}

extern "C" void kernel_launch(void* const* d_in, const int* in_sizes, int n_in,
                              void* d_out, int out_size, void* d_ws, size_t ws_size,
                              hipStream_t stream) {
    const float* h_src   = (const float*)d_in[0];
    const float* h_dst   = (const float*)d_in[1];
    const int*   src_idx = (const int*)d_in[2];
    const int*   dst_idx = (const int*)d_in[3];
    float* out = (float*)d_out;

    int E = in_sizes[2];  // number of edges

    long groups = ((long)E + EPG - 1) / EPG;
    long total_threads = groups * 32;
    int block = 256;
    long grid = (total_threads + block - 1) / block;

    edge_dot_kernel<<<(unsigned)grid, block, 0, stream>>>(h_src, h_dst, src_idx, dst_idx, out, E);
}